// Round 9
// baseline (49.527 us; speedup 1.0000x reference)
//
#include <hip/hip_runtime.h>

#define NBINS 256
#define EPSF 1e-12f
#define HSTRIDE 260   // sub-hist stride in words: 4-aligned, offsets twin by 4 banks

typedef float v4f __attribute__((ext_vector_type(4)));

// Wave-per-tile entropy: 2048 blocks x 256 threads (16 waves/CU via
// launch_bounds), wave w owns tile blockIdx.x*4+w. Fully wave-local -> zero
// barriers. Dual sub-histograms per wave (even/odd lanes, bank-offset twin)
// halve same-address atomic serialization on hot gaussian bins.
__global__ __launch_bounds__(256, 4) void entropy_kernel(const float* __restrict__ x,
                                                         float* __restrict__ ent) {
    const int lane = threadIdx.x & 63;
    const int wave = threadIdx.x >> 6;
    const int tile = (blockIdx.x << 2) + wave;    // 0..8191
    const int nc   = tile >> 4;
    const int th   = (tile >> 2) & 3;
    const int tw   = tile & 3;

    __shared__ unsigned int hist[4][2 * HSTRIDE]; // 8.3 KB, wave-private pairs

    const float* tbase = x + ((size_t)nc << 16) + (size_t)th * (64 * 256) + (size_t)tw * 64;

    // ---- load whole tile: 16 float4/lane, wave min/max ----
    v4f v[16];
    float lmin = INFINITY, lmax = -INFINITY;
#pragma unroll
    for (int k = 0; k < 16; ++k) {
        const int f   = lane + (k << 6);          // float4 index 0..1023
        const int row = f >> 4;                   // 64 rows x 16 float4
        const int c4  = f & 15;
        v[k] = *reinterpret_cast<const v4f*>(tbase + (size_t)row * 256 + c4 * 4);
        lmin = fminf(lmin, fminf(fminf(v[k].x, v[k].y), fminf(v[k].z, v[k].w)));
        lmax = fmaxf(lmax, fmaxf(fmaxf(v[k].x, v[k].y), fmaxf(v[k].z, v[k].w)));
    }
#pragma unroll
    for (int off = 32; off > 0; off >>= 1) {
        lmin = fminf(lmin, __shfl_xor(lmin, off));
        lmax = fmaxf(lmax, __shfl_xor(lmax, off));
    }

    // zero both sub-histograms (same-wave DS ops are in-order; no barrier)
    unsigned int* h0 = hist[wave];
    {
        uint4 z; z.x = z.y = z.z = z.w = 0u;
        reinterpret_cast<uint4*>(h0)[lane] = z;             // bins 0..255
        reinterpret_cast<uint4*>(h0 + HSTRIDE)[lane] = z;   // twin (1040B = 16-aligned)
    }

    const float width = (lmax - lmin) * (1.0f / NBINS);
    const float wsafe = (width > 0.0f) ? width : 1.0f;
    const float inv   = 1.0f / wsafe;             // one IEEE div; recip-mul binning
    const float coff  = -lmin * inv;

    // even lanes -> h0, odd lanes -> twin (4 banks away: no conflict on same bin)
    unsigned int* h = h0 + (lane & 1) * HSTRIDE;
#pragma unroll
    for (int k = 0; k < 16; ++k) {
        float vals[4] = {v[k].x, v[k].y, v[k].z, v[k].w};
#pragma unroll
        for (int j = 0; j < 4; ++j) {
            // arg >= -eps; trunc==floor for >=0, tiny negatives -> 0
            int bin = (int)fmaf(vals[j], inv, coff);
            bin = min(bin, 255);
            atomicAdd(&h[bin], 1u);
        }
    }

    // ---- entropy: 4 bins/lane (sum the sub-hist pair), wave-local reduce ----
    const uint4 ca = reinterpret_cast<const uint4*>(h0)[lane];
    const uint4 cb = reinterpret_cast<const uint4*>(h0 + HSTRIDE)[lane];
    const float pden = inv * (1.0f / 4096.0f);    // 1/(4096*wsafe)
    const float p0 = (float)(ca.x + cb.x) * pden + EPSF;
    const float p1 = (float)(ca.y + cb.y) * pden + EPSF;
    const float p2 = (float)(ca.z + cb.z) * pden + EPSF;
    const float p3 = (float)(ca.w + cb.w) * pden + EPSF;
    float s = p0 + p1 + p2 + p3;
#pragma unroll
    for (int off = 32; off > 0; off >>= 1) s += __shfl_xor(s, off);
    const float itot = 1.0f / s;
    const float q0 = p0 * itot, q1 = p1 * itot, q2 = p2 * itot, q3 = p3 * itot;
    float e = q0 * log2f(q0) + q1 * log2f(q1) + q2 * log2f(q2) + q3 * log2f(q3);
#pragma unroll
    for (int off = 32; off > 0; off >>= 1) e += __shfl_xor(e, off);
    if (lane == 0) ent[tile] = -e;
}

// Half-pixel bilinear upsample (4x4 -> 256x256 per nc). Proven streaming form:
// tid -> (x4, y) fixed; unrolled loop walks nc only, all weight math hoisted.
__global__ __launch_bounds__(256) void upsample_kernel(const float* __restrict__ ent,
                                                       float* __restrict__ out) {
    const int tid = blockIdx.x * blockDim.x + threadIdx.x;   // 0..524287
    const int x4  = tid & 63;
    const int y   = (tid >> 6) & 255;
    const int nc0 = tid >> 14;                                // 0..31

    const float fy  = (y + 0.5f) * 0.015625f - 0.5f;
    const float fiy = floorf(fy);
    const float wy  = fy - fiy;
    const int   iy  = (int)fiy;
    const int   y0  = max(iy, 0), y1 = min(iy + 1, 3);
    const float wy0 = 1.0f - wy;

    const int ix = (int)floorf(((x4 << 2) + 0.5f) * 0.015625f - 0.5f);
    const int x0 = max(ix, 0), x1 = min(ix + 1, 3);

    v4f wv[4];
#pragma unroll
    for (int j = 0; j < 4; ++j) {
        const float fx = ((x4 << 2) + j + 0.5f) * 0.015625f - 0.5f;
        const float wx = fx - floorf(fx);
        const float a  = 1.0f - wx, bb = wx;
        wv[j].x = ((x0 == 0) ? a : 0.0f) + ((x1 == 0) ? bb : 0.0f);
        wv[j].y = ((x0 == 1) ? a : 0.0f) + ((x1 == 1) ? bb : 0.0f);
        wv[j].z = ((x0 == 2) ? a : 0.0f) + ((x1 == 2) ? bb : 0.0f);
        wv[j].w = ((x0 == 3) ? a : 0.0f) + ((x1 == 3) ? bb : 0.0f);
    }

    const v4f* e4 = reinterpret_cast<const v4f*>(ent);  // 4 v4f rows per nc
#pragma unroll
    for (int it = 0; it < 16; ++it) {
        const int nc = nc0 + (it << 5);
        const v4f r0 = e4[nc * 4 + y0];
        const v4f r1 = e4[nc * 4 + y1];
        v4f rv = r0 * wy0 + r1 * wy;
        v4f o;
        o.x = rv.x * wv[0].x + rv.y * wv[0].y + rv.z * wv[0].z + rv.w * wv[0].w;
        o.y = rv.x * wv[1].x + rv.y * wv[1].y + rv.z * wv[1].z + rv.w * wv[1].w;
        o.z = rv.x * wv[2].x + rv.y * wv[2].y + rv.z * wv[2].z + rv.w * wv[2].w;
        o.w = rv.x * wv[3].x + rv.y * wv[3].y + rv.z * wv[3].z + rv.w * wv[3].w;
        __builtin_nontemporal_store(o, reinterpret_cast<v4f*>(out) +
                                           ((size_t)nc << 14) + (y << 6) + x4);
    }
}

extern "C" void kernel_launch(void* const* d_in, const int* in_sizes, int n_in,
                              void* d_out, int out_size, void* d_ws, size_t ws_size,
                              hipStream_t stream) {
    const float* x   = (const float*)d_in[0];
    float*       out = (float*)d_out;
    float*       ent = (float*)d_ws;     // 8192 floats = 32 KB

    entropy_kernel<<<2048, 256, 0, stream>>>(x, ent);
    upsample_kernel<<<2048, 256, 0, stream>>>(ent, out);
}

// Round 10
// 45.250 us; speedup vs baseline: 1.0945x; 1.0945x over previous
//
#include <hip/hip_runtime.h>

#define NBINS 256
#define EPSF 1e-12f

typedef float v4f __attribute__((ext_vector_type(4)));

// Fused + software-pipelined: 512 blocks x 256 threads, block = one (n,c)
// slice, wave w owns tile-row w (4 tiles, double-buffered registers: tile
// k+1's global loads in flight during tile k's histogram/entropy work).
// One barrier, then all waves upsample the 4x4 map from LDS.
// R10 change: PLAIN stores (NT-store A/B test vs R8's 48.0 µs).
__global__ __launch_bounds__(256, 2) void fused_kernel(const float* __restrict__ x,
                                                       float* __restrict__ out) {
    const int nc   = blockIdx.x;              // 0..511
    const int t    = threadIdx.x;
    const int lane = t & 63;
    const int wave = t >> 6;                  // tile-row

    __shared__ unsigned int hist[4][NBINS];   // 4 KB, wave-private
    __shared__ float ent_s[16];               // 4x4 entropy map, row-major

    const float* rbase = x + ((size_t)nc << 16) + (size_t)wave * (64 * 256);
    unsigned int* h = hist[wave];

    v4f va[16], vb[16];

#define ISSUE(buf, col)                                                           \
    _Pragma("unroll")                                                             \
    for (int k = 0; k < 16; ++k) {                                                \
        const int f = lane + (k << 6);        /* float4 idx 0..1023 */            \
        buf[k] = *reinterpret_cast<const v4f*>(                                   \
            rbase + (col) * 64 + (size_t)(f >> 4) * 256 + (f & 15) * 4);          \
    }

#define PROCESS(buf, col)                                                         \
    {                                                                             \
        float lmin = INFINITY, lmax = -INFINITY;                                  \
        _Pragma("unroll")                                                         \
        for (int k = 0; k < 16; ++k) {                                            \
            lmin = fminf(lmin, fminf(fminf(buf[k].x, buf[k].y),                   \
                                     fminf(buf[k].z, buf[k].w)));                 \
            lmax = fmaxf(lmax, fmaxf(fmaxf(buf[k].x, buf[k].y),                   \
                                     fmaxf(buf[k].z, buf[k].w)));                 \
        }                                                                         \
        _Pragma("unroll")                                                         \
        for (int off = 32; off > 0; off >>= 1) {                                  \
            lmin = fminf(lmin, __shfl_xor(lmin, off));                            \
            lmax = fmaxf(lmax, __shfl_xor(lmax, off));                            \
        }                                                                         \
        uint4 z; z.x = z.y = z.z = z.w = 0u;  /* same-wave DS ops in-order */     \
        reinterpret_cast<uint4*>(h)[lane] = z;                                    \
        const float width = (lmax - lmin) * (1.0f / NBINS);                       \
        const float wsafe = (width > 0.0f) ? width : 1.0f;                        \
        const float inv   = 1.0f / wsafe;                                         \
        const float coff  = -lmin * inv;                                          \
        _Pragma("unroll")                                                         \
        for (int k = 0; k < 16; ++k) {                                            \
            float vals[4] = {buf[k].x, buf[k].y, buf[k].z, buf[k].w};             \
            _Pragma("unroll")                                                     \
            for (int j = 0; j < 4; ++j) {                                         \
                /* arg >= -eps; trunc==floor for >=0, tiny negatives -> 0 */      \
                int bin = (int)fmaf(vals[j], inv, coff);                          \
                bin = min(bin, 255);                                              \
                atomicAdd(&h[bin], 1u);                                           \
            }                                                                     \
        }                                                                         \
        const uint4 c    = reinterpret_cast<const uint4*>(h)[lane];               \
        const float pden = inv * (1.0f / 4096.0f);  /* 1/(4096*wsafe) */          \
        const float p0 = (float)c.x * pden + EPSF;                                \
        const float p1 = (float)c.y * pden + EPSF;                                \
        const float p2 = (float)c.z * pden + EPSF;                                \
        const float p3 = (float)c.w * pden + EPSF;                                \
        float s = p0 + p1 + p2 + p3;                                              \
        _Pragma("unroll")                                                         \
        for (int off = 32; off > 0; off >>= 1) s += __shfl_xor(s, off);           \
        const float itot = 1.0f / s;                                              \
        const float q0 = p0 * itot, q1 = p1 * itot;                               \
        const float q2 = p2 * itot, q3 = p3 * itot;                               \
        float e = q0 * log2f(q0) + q1 * log2f(q1)                                 \
                + q2 * log2f(q2) + q3 * log2f(q3);                                \
        _Pragma("unroll")                                                         \
        for (int off = 32; off > 0; off >>= 1) e += __shfl_xor(e, off);           \
        if (lane == 0) ent_s[(wave << 2) + (col)] = -e;                           \
    }

    // pipeline: loads of tile k+1 in flight during PROCESS of tile k
    ISSUE(va, 0)
    ISSUE(vb, 1)
    PROCESS(va, 0)
    ISSUE(va, 2)
    PROCESS(vb, 1)
    ISSUE(vb, 3)
    PROCESS(va, 2)
    PROCESS(vb, 3)
#undef ISSUE
#undef PROCESS

    __syncthreads();

    // ---- upsample 4x4 -> 256x256 from LDS ----
    const int x4 = t & 63;
    const int yy = wave;

    // horizontal weights hoisted: ix uniform over this lane's 4 pixels
    const int ix = (int)floorf(((x4 << 2) + 0.5f) * 0.015625f - 0.5f);
    const int x0 = max(ix, 0), x1 = min(ix + 1, 3);
    v4f wv[4];
#pragma unroll
    for (int j = 0; j < 4; ++j) {
        const float fx = ((x4 << 2) + j + 0.5f) * 0.015625f - 0.5f;
        const float wx = fx - floorf(fx);
        const float a  = 1.0f - wx, bb = wx;
        wv[j].x = ((x0 == 0) ? a : 0.0f) + ((x1 == 0) ? bb : 0.0f);
        wv[j].y = ((x0 == 1) ? a : 0.0f) + ((x1 == 1) ? bb : 0.0f);
        wv[j].z = ((x0 == 2) ? a : 0.0f) + ((x1 == 2) ? bb : 0.0f);
        wv[j].w = ((x0 == 3) ? a : 0.0f) + ((x1 == 3) ? bb : 0.0f);
    }

    const v4f* er = reinterpret_cast<const v4f*>(ent_s);   // 4 rows of 4
    v4f* out4 = reinterpret_cast<v4f*>(out) + ((size_t)nc << 14);
#pragma unroll 8
    for (int it = 0; it < 64; ++it) {
        const int   y   = (it << 2) + yy;
        const float fy  = (y + 0.5f) * 0.015625f - 0.5f;
        const float fiy = floorf(fy);
        const float wy  = fy - fiy;
        const int   iy  = (int)fiy;
        const int   y0  = max(iy, 0), y1 = min(iy + 1, 3);
        const float wy0 = 1.0f - wy;

        const v4f r0 = er[y0];            // uniform per wave -> LDS broadcast
        const v4f r1 = er[y1];
        v4f rv = r0 * wy0 + r1 * wy;
        v4f o;
        o.x = rv.x * wv[0].x + rv.y * wv[0].y + rv.z * wv[0].z + rv.w * wv[0].w;
        o.y = rv.x * wv[1].x + rv.y * wv[1].y + rv.z * wv[1].z + rv.w * wv[1].w;
        o.z = rv.x * wv[2].x + rv.y * wv[2].y + rv.z * wv[2].z + rv.w * wv[2].w;
        o.w = rv.x * wv[3].x + rv.y * wv[3].y + rv.z * wv[3].z + rv.w * wv[3].w;
        out4[(y << 6) + x4] = o;          // plain store (A/B vs R8's NT)
    }
}

extern "C" void kernel_launch(void* const* d_in, const int* in_sizes, int n_in,
                              void* d_out, int out_size, void* d_ws, size_t ws_size,
                              hipStream_t stream) {
    const float* x   = (const float*)d_in[0];
    float*       out = (float*)d_out;
    fused_kernel<<<512, 256, 0, stream>>>(x, out);
}

// Round 11
// 43.437 us; speedup vs baseline: 1.1402x; 1.0418x over previous
//
#include <hip/hip_runtime.h>

#define NBINS 256
#define EPSF 1e-12f

typedef float v4f __attribute__((ext_vector_type(4)));

// Fused, pipelined, write-interleaved: 512 blocks x 256 threads, block = one
// (n,c) slice. Wave w owns tile COLUMN w and processes tiles (s,w) for
// s=0..3 with double-buffered registers, so entropy ROW s is complete after
// step s. Output quarter q (rows 64q..64q+63) needs only ent rows q-1..q+1,
// so quarter writes are interleaved into the hist pipeline:
//   rows 0,1 done -> write q0 ; row 2 done -> write q1 ; row 3 -> q2,q3.
// HBM reads (tile loads) and writes (quarters) overlap for the middle half
// of the block instead of being fully phase-serial. Plain stores (R10 win).
__global__ __launch_bounds__(256, 2) void fused_kernel(const float* __restrict__ x,
                                                       float* __restrict__ out) {
    const int nc   = blockIdx.x;              // 0..511
    const int t    = threadIdx.x;
    const int lane = t & 63;
    const int wave = t >> 6;                  // tile COLUMN

    __shared__ unsigned int hist[4][NBINS];   // 4 KB, wave-private
    __shared__ float ent_s[16];               // 4x4 entropy map, row-major

    const float* cbase = x + ((size_t)nc << 16) + (size_t)wave * 64;
    unsigned int* h = hist[wave];

    v4f va[16], vb[16];

#define ISSUE(buf, s)                                                             \
    _Pragma("unroll")                                                             \
    for (int k = 0; k < 16; ++k) {                                                \
        const int f = lane + (k << 6);        /* float4 idx 0..1023 */            \
        buf[k] = *reinterpret_cast<const v4f*>(                                   \
            cbase + (size_t)(s) * (64 * 256) + (size_t)(f >> 4) * 256 + (f & 15) * 4); \
    }

#define PROCESS(buf, s)                                                           \
    {                                                                             \
        float lmin = INFINITY, lmax = -INFINITY;                                  \
        _Pragma("unroll")                                                         \
        for (int k = 0; k < 16; ++k) {                                            \
            lmin = fminf(lmin, fminf(fminf(buf[k].x, buf[k].y),                   \
                                     fminf(buf[k].z, buf[k].w)));                 \
            lmax = fmaxf(lmax, fmaxf(fmaxf(buf[k].x, buf[k].y),                   \
                                     fmaxf(buf[k].z, buf[k].w)));                 \
        }                                                                         \
        _Pragma("unroll")                                                         \
        for (int off = 32; off > 0; off >>= 1) {                                  \
            lmin = fminf(lmin, __shfl_xor(lmin, off));                            \
            lmax = fmaxf(lmax, __shfl_xor(lmax, off));                            \
        }                                                                         \
        uint4 z; z.x = z.y = z.z = z.w = 0u;  /* same-wave DS ops in-order */     \
        reinterpret_cast<uint4*>(h)[lane] = z;                                    \
        const float width = (lmax - lmin) * (1.0f / NBINS);                       \
        const float wsafe = (width > 0.0f) ? width : 1.0f;                        \
        const float inv   = 1.0f / wsafe;                                         \
        const float coff  = -lmin * inv;                                          \
        _Pragma("unroll")                                                         \
        for (int k = 0; k < 16; ++k) {                                            \
            float vals[4] = {buf[k].x, buf[k].y, buf[k].z, buf[k].w};             \
            _Pragma("unroll")                                                     \
            for (int j = 0; j < 4; ++j) {                                         \
                /* arg >= -eps; trunc==floor for >=0, tiny negatives -> 0 */      \
                int bin = (int)fmaf(vals[j], inv, coff);                          \
                bin = min(bin, 255);                                              \
                atomicAdd(&h[bin], 1u);                                           \
            }                                                                     \
        }                                                                         \
        const uint4 c    = reinterpret_cast<const uint4*>(h)[lane];               \
        const float pden = inv * (1.0f / 4096.0f);  /* 1/(4096*wsafe) */          \
        const float p0 = (float)c.x * pden + EPSF;                                \
        const float p1 = (float)c.y * pden + EPSF;                                \
        const float p2 = (float)c.z * pden + EPSF;                                \
        const float p3 = (float)c.w * pden + EPSF;                                \
        float s_ = p0 + p1 + p2 + p3;                                             \
        _Pragma("unroll")                                                         \
        for (int off = 32; off > 0; off >>= 1) s_ += __shfl_xor(s_, off);         \
        const float itot = 1.0f / s_;                                             \
        const float q0 = p0 * itot, q1 = p1 * itot;                               \
        const float q2 = p2 * itot, q3 = p3 * itot;                               \
        float e = q0 * log2f(q0) + q1 * log2f(q1)                                 \
                + q2 * log2f(q2) + q3 * log2f(q3);                                \
        _Pragma("unroll")                                                         \
        for (int off = 32; off > 0; off >>= 1) e += __shfl_xor(e, off);           \
        if (lane == 0) ent_s[((s) << 2) + wave] = -e;                             \
    }

    // ---- horizontal upsample weights (lane = x4), hoisted once ----
    const int x4 = lane;
    const int ix = (int)floorf(((x4 << 2) + 0.5f) * 0.015625f - 0.5f);
    const int x0 = max(ix, 0), x1 = min(ix + 1, 3);
    v4f wv[4];
#pragma unroll
    for (int j = 0; j < 4; ++j) {
        const float fx = ((x4 << 2) + j + 0.5f) * 0.015625f - 0.5f;
        const float wx = fx - floorf(fx);
        const float a  = 1.0f - wx, bb = wx;
        wv[j].x = ((x0 == 0) ? a : 0.0f) + ((x1 == 0) ? bb : 0.0f);
        wv[j].y = ((x0 == 1) ? a : 0.0f) + ((x1 == 1) ? bb : 0.0f);
        wv[j].z = ((x0 == 2) ? a : 0.0f) + ((x1 == 2) ? bb : 0.0f);
        wv[j].w = ((x0 == 3) ? a : 0.0f) + ((x1 == 3) ? bb : 0.0f);
    }
    const v4f* er = reinterpret_cast<const v4f*>(ent_s);   // 4 rows of 4
    v4f* out4 = reinterpret_cast<v4f*>(out) + ((size_t)nc << 14);

    // quarter q, wave handles rows 64q + 16*wave + i (one 1KB store per row)
#define WQ(q)                                                                     \
    _Pragma("unroll")                                                             \
    for (int i = 0; i < 16; ++i) {                                                \
        const int   y   = ((q) << 6) + (wave << 4) + i;                           \
        const float fy  = (y + 0.5f) * 0.015625f - 0.5f;                          \
        const float fiy = floorf(fy);                                             \
        const float wy  = fy - fiy;                                               \
        const int   iy  = (int)fiy;                                               \
        const int   y0  = max(iy, 0), y1 = min(iy + 1, 3);                        \
        const v4f r0 = er[y0];            /* uniform per wave -> broadcast */     \
        const v4f r1 = er[y1];                                                    \
        v4f rv = r0 * (1.0f - wy) + r1 * wy;                                      \
        v4f o;                                                                    \
        o.x = rv.x * wv[0].x + rv.y * wv[0].y + rv.z * wv[0].z + rv.w * wv[0].w;  \
        o.y = rv.x * wv[1].x + rv.y * wv[1].y + rv.z * wv[1].z + rv.w * wv[1].w;  \
        o.z = rv.x * wv[2].x + rv.y * wv[2].y + rv.z * wv[2].z + rv.w * wv[2].w;  \
        o.w = rv.x * wv[3].x + rv.y * wv[3].y + rv.z * wv[3].z + rv.w * wv[3].w;  \
        out4[(y << 6) + x4] = o;                                                  \
    }

    // ---- pipelined schedule: loads ahead, writes interleaved ----
    ISSUE(va, 0)
    ISSUE(vb, 1)
    PROCESS(va, 0)          // ent row 0 (this wave's column entry)
    ISSUE(va, 2)
    PROCESS(vb, 1)          // ent row 1
    ISSUE(vb, 3)
    __syncthreads();        // ent rows 0,1 complete across all waves
    WQ(0)                   // rows 0..63   (needs ent rows 0,1)
    PROCESS(va, 2)          // ent row 2
    __syncthreads();        // ent row 2 complete
    WQ(1)                   // rows 64..127 (needs ent rows 0,1,2)
    PROCESS(vb, 3)          // ent row 3
    __syncthreads();        // ent row 3 complete
    WQ(2)                   // rows 128..191 (needs ent rows 1,2,3)
    WQ(3)                   // rows 192..255 (needs ent rows 2,3)

#undef ISSUE
#undef PROCESS
#undef WQ
}

extern "C" void kernel_launch(void* const* d_in, const int* in_sizes, int n_in,
                              void* d_out, int out_size, void* d_ws, size_t ws_size,
                              hipStream_t stream) {
    const float* x   = (const float*)d_in[0];
    float*       out = (float*)d_out;
    fused_kernel<<<512, 256, 0, stream>>>(x, out);
}